// Round 1
// baseline (238.886 us; speedup 1.0000x reference)
//
#include <hip/hip_runtime.h>
#include <cstdint>
#include <cstddef>

typedef __attribute__((ext_vector_type(8))) short bf16x8;
typedef __attribute__((ext_vector_type(4))) float f32x4;

__device__ __forceinline__ short f2bf(float f) {
  unsigned u = __float_as_uint(f);
  u += 0x7FFFu + ((u >> 16) & 1u);
  return (short)(u >> 16);
}

// timescale[r] = 10000^(r/16) = 10^(r/4); these are 1/timescale
__constant__ float INV_TS[8] = {
  1.0f, 0.5623413251903491f, 0.31622776601683794f, 0.17782794100389228f,
  0.1f, 0.05623413251903491f, 0.031622776601683794f, 0.017782794100389228f
};

// ---------------------------------------------------------------------------
// GEMM: C[M x Ntot] = X[M x 256] @ W[* x 256]^T + bias   (fp32 VALU)
// BM=BN=128, BK=16, 256 threads, 8x8 per thread. Column-block picks W0/W1/W2
// (each 256 cols wide). Grid: (M/128, Ntot/128).
// ---------------------------------------------------------------------------
__global__ __launch_bounds__(256) void gemm_xwt(
    const float* __restrict__ X,
    const float* __restrict__ W0, const float* __restrict__ W1, const float* __restrict__ W2,
    const float* __restrict__ b0, const float* __restrict__ b1, const float* __restrict__ b2,
    float* __restrict__ C, int Ntot)
{
  __shared__ float sX[16][136];   // [kk][row], stride 136 (544B, 16B-aligned rows)
  __shared__ float sW[16][136];
  const int t = threadIdx.x;
  const int rbase = blockIdx.x * 128;
  const int cgbase = blockIdx.y * 128;
  const int mat = cgbase >> 8;
  const float* W = (mat == 0) ? W0 : ((mat == 1) ? W1 : W2);
  const float* bias = (mat == 0) ? b0 : ((mat == 1) ? b1 : b2);
  const int wbase = cgbase & 255;

  const int tr = t >> 4, tc = t & 15;
  const int lrow = t >> 1, lk = (t & 1) * 8;

  const float* Xg = X + (size_t)(rbase + lrow) * 256 + lk;
  const float* Wg = W + (size_t)(wbase + lrow) * 256 + lk;

  float acc[8][8];
#pragma unroll
  for (int j = 0; j < 8; ++j)
#pragma unroll
    for (int i = 0; i < 8; ++i) acc[j][i] = 0.f;

  for (int k0 = 0; k0 < 256; k0 += 16) {
    f32x4 xv0 = *(const f32x4*)(Xg + k0);
    f32x4 xv1 = *(const f32x4*)(Xg + k0 + 4);
    f32x4 wv0 = *(const f32x4*)(Wg + k0);
    f32x4 wv1 = *(const f32x4*)(Wg + k0 + 4);
    __syncthreads();
#pragma unroll
    for (int u = 0; u < 4; ++u) {
      sX[lk + u][lrow]     = xv0[u];
      sX[lk + 4 + u][lrow] = xv1[u];
      sW[lk + u][lrow]     = wv0[u];
      sW[lk + 4 + u][lrow] = wv1[u];
    }
    __syncthreads();
#pragma unroll
    for (int kk = 0; kk < 16; ++kk) {
      f32x4 a0  = *(const f32x4*)&sX[kk][tr * 8];
      f32x4 a1  = *(const f32x4*)&sX[kk][tr * 8 + 4];
      f32x4 bv0 = *(const f32x4*)&sW[kk][tc * 8];
      f32x4 bv1 = *(const f32x4*)&sW[kk][tc * 8 + 4];
#pragma unroll
      for (int j = 0; j < 4; ++j)
#pragma unroll
        for (int i = 0; i < 4; ++i) {
          acc[j][i]         += a0[j] * bv0[i];
          acc[j][i + 4]     += a0[j] * bv1[i];
          acc[j + 4][i]     += a1[j] * bv0[i];
          acc[j + 4][i + 4] += a1[j] * bv1[i];
        }
    }
  }
#pragma unroll
  for (int j = 0; j < 8; ++j) {
    size_t r = (size_t)(rbase + tr * 8 + j);
#pragma unroll
    for (int i = 0; i < 8; ++i) {
      int c = tc * 8 + i;
      C[r * (size_t)Ntot + cgbase + c] = acc[j][i] + bias[wbase + c];
    }
  }
}

// ---------------------------------------------------------------------------
// RoPE + scale + pack to bf16. QKV: [8192][768] f32 (q|k|v each 256 cols).
// Q,K out: [16][4096][32] bf16. V out TRANSPOSED: [16][32][4096] bf16.
// One thread per (row, mat, head, dh<16): handles the (dh, dh+16) pair.
// ---------------------------------------------------------------------------
__global__ __launch_bounds__(256) void rope_pack(
    const float* __restrict__ QKV,
    short* __restrict__ Qo, short* __restrict__ Ko, short* __restrict__ Vo)
{
  const int id = blockIdx.x * 256 + threadIdx.x;   // < 8192*384
  const int dh = id & 15;
  const int hh = (id >> 4) & 7;
  const int r7 = id >> 7;
  const int mt = r7 % 3;
  const int row = r7 / 3;
  const int b = row >> 12, n = row & 4095;
  const int bh = b * 8 + hh;
  const float* src = QKV + (size_t)row * 768 + mt * 256 + hh * 32 + dh;
  float v0 = src[0], v1 = src[16];
  if (mt == 0) { v0 *= 0.17677669529663687f; v1 *= 0.17677669529663687f; } // hd^-0.5
  if (mt < 2) {
    if (dh < 8) {   // rotated pair (dh, dh+16); dims 8..15 / 24..31 pass through
      float ang = (float)n * INV_TS[dh];
      float s = sinf(ang), c = cosf(ang);
      float r0 = v0 * c - v1 * s;
      float r1 = v1 * c + v0 * s;
      v0 = r0; v1 = r1;
    }
    short* dst = (mt == 0 ? Qo : Ko) + (size_t)bh * 4096 * 32 + n * 32 + dh;
    dst[0]  = f2bf(v0);
    dst[16] = f2bf(v1);
  } else {
    short* dst = Vo + (size_t)bh * 32 * 4096 + (size_t)dh * 4096 + n;
    dst[0]         = f2bf(v0);
    dst[16 * 4096] = f2bf(v1);
  }
}

// ---------------------------------------------------------------------------
// Flash attention, bf16 MFMA 16x16x32, no-max softmax (scores bounded).
// Block: 256 threads = 4 waves; 64 q-rows per block (16 per wave).
// K-tiles of 64 keys. LDS padded stride 72 elems (144B, 16B-aligned).
// Grid: (4096/64, 16). Output Ao: [2][4096][256] f32 (B,N,H*hd).
// ---------------------------------------------------------------------------
__global__ __launch_bounds__(256) void attn_fwd(
    const short* __restrict__ Qg, const short* __restrict__ Kg, const short* __restrict__ Vg,
    const float* __restrict__ ab, const int* __restrict__ slp,
    float* __restrict__ Ao)
{
  __shared__ short sK[64 * 72];   // [key][dim]
  __shared__ short sV[32 * 72];   // [dim][key]  (V transposed)
  __shared__ short sP[64 * 72];   // Q staging, then per-wave P tiles (16x64 each)
  const int t = threadIdx.x;
  const int w = t >> 6;
  const int l = t & 63;
  const int l15 = l & 15, lg = l >> 4;
  const int bh = blockIdx.y;
  const int h = bh & 7;
  const int qbase = blockIdx.x * 64;
  const int sl = *slp;

  const short* Qb = Qg + (size_t)bh * 4096 * 32;
  const short* Kb = Kg + (size_t)bh * 4096 * 32;
  const short* Vb = Vg + (size_t)bh * 32 * 4096;

  { // stage Q tile (64x32) into sP
    int row = t >> 2, d0 = (t & 3) * 8;
    *(bf16x8*)(sP + row * 72 + d0) = *(const bf16x8*)(Qb + (size_t)(qbase + row) * 32 + d0);
  }
  __syncthreads();
  // A-frag: lane l -> q-row (w*16 + l&15), dims (l>>4)*8 .. +8
  bf16x8 qf = *(const bf16x8*)(sP + (w * 16 + l15) * 72 + lg * 8);
  __syncthreads();   // Q reads complete before sP is reused for P

  const f32x4 fzero = {0.f, 0.f, 0.f, 0.f};
  f32x4 Oacc[2];
  Oacc[0] = fzero; Oacc[1] = fzero;
  float den[4] = {0.f, 0.f, 0.f, 0.f};

  int qv[4];
#pragma unroll
  for (int j = 0; j < 4; ++j) qv[j] = (qbase + w * 16 + lg * 4 + j) / sl;
  const float bsame = ab[h * 2], bdiff = ab[h * 2 + 1];

  const int srow = t >> 2, sd0 = (t & 3) * 8;    // K staging
  const int svd = t >> 3, skoff = (t & 7) * 8;   // V staging

  for (int kt = 0; kt < 64; ++kt) {
    const int kb0 = kt << 6;
    bf16x8 kv = *(const bf16x8*)(Kb + (size_t)(kb0 + srow) * 32 + sd0);
    bf16x8 vv = *(const bf16x8*)(Vb + (size_t)svd * 4096 + kb0 + skoff);
    __syncthreads();    // previous iteration's compute done
    *(bf16x8*)(sK + srow * 72 + sd0) = kv;
    *(bf16x8*)(sV + svd * 72 + skoff) = vv;
    __syncthreads();

    // S = Q(16x32) . K^T(32x64) : 4 MFMAs. B-frag: col=key=l&15+16t, k=dim=(l>>4)*8+j
    f32x4 S[4];
#pragma unroll
    for (int t4 = 0; t4 < 4; ++t4) {
      bf16x8 kf = *(const bf16x8*)(sK + (t4 * 16 + l15) * 72 + lg * 8);
      S[t4] = __builtin_amdgcn_mfma_f32_16x16x32_bf16(qf, kf, fzero, 0, 0, 0);
    }
    // bias + exp + den accumulate + P write (D-layout: row=(l>>4)*4+j, col=l&15+16t)
#pragma unroll
    for (int t4 = 0; t4 < 4; ++t4) {
      const int gcol = kb0 + t4 * 16 + l15;
      const int kvr = gcol / sl;
#pragma unroll
      for (int j = 0; j < 4; ++j) {
        float p = __expf(S[t4][j] + ((qv[j] == kvr) ? bsame : bdiff));
        den[j] += p;
        sP[w * 1152 + (lg * 4 + j) * 72 + t4 * 16 + l15] = f2bf(p);
      }
    }
    // O += P(16x64) . V(64x32), two K=32 chunks x two 16-col tiles
#pragma unroll
    for (int kk = 0; kk < 2; ++kk) {
      bf16x8 pf = *(const bf16x8*)(sP + w * 1152 + l15 * 72 + kk * 32 + lg * 8);
#pragma unroll
      for (int nt = 0; nt < 2; ++nt) {
        bf16x8 vf = *(const bf16x8*)(sV + (nt * 16 + l15) * 72 + kk * 32 + lg * 8);
        Oacc[nt] = __builtin_amdgcn_mfma_f32_16x16x32_bf16(pf, vf, Oacc[nt], 0, 0, 0);
      }
    }
    __syncthreads();
  }

  // reduce den across the 16 lanes of each row-group (cols of S)
#pragma unroll
  for (int j = 0; j < 4; ++j) {
    den[j] += __shfl_xor(den[j], 1, 64);
    den[j] += __shfl_xor(den[j], 2, 64);
    den[j] += __shfl_xor(den[j], 4, 64);
    den[j] += __shfl_xor(den[j], 8, 64);
  }

  const int b = bh >> 3;
#pragma unroll
  for (int nt = 0; nt < 2; ++nt)
#pragma unroll
    for (int j = 0; j < 4; ++j) {
      const int n = qbase + w * 16 + lg * 4 + j;
      const int col = h * 32 + nt * 16 + l15;
      Ao[((size_t)(b * 4096 + n)) * 256 + col] = Oacc[nt][j] / den[j];
    }
}

// ---------------------------------------------------------------------------
extern "C" void kernel_launch(void* const* d_in, const int* in_sizes, int n_in,
                              void* d_out, int out_size, void* d_ws, size_t ws_size,
                              hipStream_t stream) {
  (void)in_sizes; (void)n_in; (void)out_size; (void)ws_size;
  const float* hs = (const float*)d_in[0];
  const float* qw = (const float*)d_in[1];
  const float* qb = (const float*)d_in[2];
  const float* kw = (const float*)d_in[3];
  const float* kb = (const float*)d_in[4];
  const float* vw = (const float*)d_in[5];
  const float* vb = (const float*)d_in[6];
  const float* ow = (const float*)d_in[7];
  const float* ob = (const float*)d_in[8];
  const float* ab = (const float*)d_in[9];
  const int* sl   = (const int*)d_in[11];
  float* out = (float*)d_out;

  char* ws = (char*)d_ws;
  float* qkv   = (float*)(ws);                 // 8192*768 f32  = 25165824 B
  float* attno = (float*)(ws + 25165824);      // 8192*256 f32  =  8388608 B
  short* Qbf   = (short*)(ws + 33554432);      // 16*4096*32 bf16 = 4194304 B
  short* Kbf   = (short*)(ws + 37748736);      // 4194304 B
  short* Vtb   = (short*)(ws + 41943040);      // 4194304 B (transposed)

  // QKV projection: [8192x256] @ [768x256]^T + bias
  gemm_xwt<<<dim3(64, 6), 256, 0, stream>>>(hs, qw, kw, vw, qb, kb, vb, qkv, 768);
  // RoPE + scale + bf16 pack (V transposed)
  rope_pack<<<dim3(12288), 256, 0, stream>>>(qkv, Qbf, Kbf, Vtb);
  // attention
  attn_fwd<<<dim3(64, 16), 256, 0, stream>>>(Qbf, Kbf, Vtb, ab, sl, attno);
  // output projection: [8192x256] @ [256x256]^T + bias
  gemm_xwt<<<dim3(64, 2), 256, 0, stream>>>(attno, ow, ow, ow, ob, ob, ob, out, 256);
}

// Round 2
// 206.117 us; speedup vs baseline: 1.1590x; 1.1590x over previous
//
#include <hip/hip_runtime.h>
#include <cstdint>
#include <cstddef>

typedef __attribute__((ext_vector_type(8))) short bf16x8;
typedef __attribute__((ext_vector_type(4))) float f32x4;
typedef __attribute__((ext_vector_type(2))) unsigned int u32x2;

extern "C" __device__ float __ocml_native_exp2_f32(float);
#define EXP2 __ocml_native_exp2_f32

__device__ __forceinline__ unsigned cvt_pk_bf16(float a, float b) {
  unsigned r;
  asm("v_cvt_pk_bf16_f32 %0, %1, %2" : "=v"(r) : "v"(a), "v"(b));
  return r;
}

__device__ __forceinline__ short f2bf(float f) {
  unsigned u = __float_as_uint(f);
  u += 0x7FFFu + ((u >> 16) & 1u);
  return (short)(u >> 16);
}

// timescale[r] = 10000^(r/16) = 10^(r/4); these are 1/timescale
__constant__ float INV_TS[8] = {
  1.0f, 0.5623413251903491f, 0.31622776601683794f, 0.17782794100389228f,
  0.1f, 0.05623413251903491f, 0.031622776601683794f, 0.017782794100389228f
};

// ---------------------------------------------------------------------------
// GEMM: C[M x Ntot] = X[M x 256] @ W[* x 256]^T + bias   (fp32 VALU)
// ---------------------------------------------------------------------------
__global__ __launch_bounds__(256) void gemm_xwt(
    const float* __restrict__ X,
    const float* __restrict__ W0, const float* __restrict__ W1, const float* __restrict__ W2,
    const float* __restrict__ b0, const float* __restrict__ b1, const float* __restrict__ b2,
    float* __restrict__ C, int Ntot)
{
  __shared__ float sX[16][136];
  __shared__ float sW[16][136];
  const int t = threadIdx.x;
  const int rbase = blockIdx.x * 128;
  const int cgbase = blockIdx.y * 128;
  const int mat = cgbase >> 8;
  const float* W = (mat == 0) ? W0 : ((mat == 1) ? W1 : W2);
  const float* bias = (mat == 0) ? b0 : ((mat == 1) ? b1 : b2);
  const int wbase = cgbase & 255;

  const int tr = t >> 4, tc = t & 15;
  const int lrow = t >> 1, lk = (t & 1) * 8;

  const float* Xg = X + (size_t)(rbase + lrow) * 256 + lk;
  const float* Wg = W + (size_t)(wbase + lrow) * 256 + lk;

  float acc[8][8];
#pragma unroll
  for (int j = 0; j < 8; ++j)
#pragma unroll
    for (int i = 0; i < 8; ++i) acc[j][i] = 0.f;

  for (int k0 = 0; k0 < 256; k0 += 16) {
    f32x4 xv0 = *(const f32x4*)(Xg + k0);
    f32x4 xv1 = *(const f32x4*)(Xg + k0 + 4);
    f32x4 wv0 = *(const f32x4*)(Wg + k0);
    f32x4 wv1 = *(const f32x4*)(Wg + k0 + 4);
    __syncthreads();
#pragma unroll
    for (int u = 0; u < 4; ++u) {
      sX[lk + u][lrow]     = xv0[u];
      sX[lk + 4 + u][lrow] = xv1[u];
      sW[lk + u][lrow]     = wv0[u];
      sW[lk + 4 + u][lrow] = wv1[u];
    }
    __syncthreads();
#pragma unroll
    for (int kk = 0; kk < 16; ++kk) {
      f32x4 a0  = *(const f32x4*)&sX[kk][tr * 8];
      f32x4 a1  = *(const f32x4*)&sX[kk][tr * 8 + 4];
      f32x4 bv0 = *(const f32x4*)&sW[kk][tc * 8];
      f32x4 bv1 = *(const f32x4*)&sW[kk][tc * 8 + 4];
#pragma unroll
      for (int j = 0; j < 4; ++j)
#pragma unroll
        for (int i = 0; i < 4; ++i) {
          acc[j][i]         += a0[j] * bv0[i];
          acc[j][i + 4]     += a0[j] * bv1[i];
          acc[j + 4][i]     += a1[j] * bv0[i];
          acc[j + 4][i + 4] += a1[j] * bv1[i];
        }
    }
  }
#pragma unroll
  for (int j = 0; j < 8; ++j) {
    size_t r = (size_t)(rbase + tr * 8 + j);
#pragma unroll
    for (int i = 0; i < 8; ++i) {
      int c = tc * 8 + i;
      C[r * (size_t)Ntot + cgbase + c] = acc[j][i] + bias[wbase + c];
    }
  }
}

// ---------------------------------------------------------------------------
// RoPE + scale + pack to bf16. Q,K: [16][4096][32]. V TRANSPOSED: [16][32][4096].
// ---------------------------------------------------------------------------
__global__ __launch_bounds__(256) void rope_pack(
    const float* __restrict__ QKV,
    short* __restrict__ Qo, short* __restrict__ Ko, short* __restrict__ Vo)
{
  const int id = blockIdx.x * 256 + threadIdx.x;
  const int dh = id & 15;
  const int hh = (id >> 4) & 7;
  const int r7 = id >> 7;
  const int mt = r7 % 3;
  const int row = r7 / 3;
  const int b = row >> 12, n = row & 4095;
  const int bh = b * 8 + hh;
  const float* src = QKV + (size_t)row * 768 + mt * 256 + hh * 32 + dh;
  float v0 = src[0], v1 = src[16];
  if (mt == 0) { v0 *= 0.17677669529663687f; v1 *= 0.17677669529663687f; }
  if (mt < 2) {
    if (dh < 8) {
      float ang = (float)n * INV_TS[dh];
      float s = sinf(ang), c = cosf(ang);
      float r0 = v0 * c - v1 * s;
      float r1 = v1 * c + v0 * s;
      v0 = r0; v1 = r1;
    }
    short* dst = (mt == 0 ? Qo : Ko) + (size_t)bh * 4096 * 32 + n * 32 + dh;
    dst[0]  = f2bf(v0);
    dst[16] = f2bf(v1);
  } else {
    short* dst = Vo + (size_t)bh * 32 * 4096 + (size_t)dh * 4096 + n;
    dst[0]         = f2bf(v0);
    dst[16 * 4096] = f2bf(v1);
  }
}

// ---------------------------------------------------------------------------
// Flash attention v2: barrier-free, S^T orientation, packed P writes.
// Block 256 = 4 independent waves; each wave owns 32 q-rows.
// K/V read direct from global (L2-resident) with 1-tile register prefetch.
// Grid: (4096/128, 16).
// ---------------------------------------------------------------------------
__global__ __launch_bounds__(256, 2) void attn_fwd(
    const short* __restrict__ Qg, const short* __restrict__ Kg, const short* __restrict__ Vg,
    const float* __restrict__ ab, const int* __restrict__ slp,
    float* __restrict__ Ao)
{
  __shared__ short sP[4][32 * 72];   // per-wave P tile [32 q][64 k], stride 72
  const int t = threadIdx.x, w = t >> 6, l = t & 63;
  const int l15 = l & 15, lg = l >> 4;
  const int bh = blockIdx.y, h = bh & 7;
  const int qb = blockIdx.x * 128 + w * 32;
  const int sl = *slp;

  const short* Qb = Qg + (size_t)bh * (4096 * 32);
  const short* Kb = Kg + (size_t)bh * (4096 * 32);
  const short* Vb = Vg + (size_t)bh * (32 * 4096);

  bf16x8 qf[2];
  qf[0] = *(const bf16x8*)(Qb + (size_t)(qb + l15) * 32 + lg * 8);
  qf[1] = *(const bf16x8*)(Qb + (size_t)(qb + 16 + l15) * 32 + lg * 8);

  const float LOG2E = 1.4426950408889634f;
  const float lbs = ab[h * 2] * LOG2E, lbd = ab[h * 2 + 1] * LOG2E;
  const int qrow[2] = { qb + l15, qb + 16 + l15 };
  const int qv[2]   = { qrow[0] / sl, qrow[1] / sl };
  const int qlo[2]  = { qv[0] * sl, qv[1] * sl };

  short* P = &sP[w][0];
  short* pw = P + l15 * 72 + lg * 4;         // packed write base (row=q, col=k)
  const short* pr = P + l15 * 72 + lg * 8;   // A-frag read base

  const f32x4 fz = {0.f, 0.f, 0.f, 0.f};
  f32x4 Oacc[2][2];
  Oacc[0][0] = fz; Oacc[0][1] = fz; Oacc[1][0] = fz; Oacc[1][1] = fz;
  float den[2] = {0.f, 0.f};

  // fragment pointers (per-lane): K row = l15 (+t4*16), dims lg*8
  const short* kp = Kb + (size_t)l15 * 32 + lg * 8;
  const short* vp = Vb + (size_t)l15 * 4096 + lg * 8;

  bf16x8 kc[4], vc[4];
#pragma unroll
  for (int t4 = 0; t4 < 4; ++t4) kc[t4] = *(const bf16x8*)(kp + t4 * 512);
  vc[0] = *(const bf16x8*)(vp);
  vc[1] = *(const bf16x8*)(vp + 32);
  vc[2] = *(const bf16x8*)(vp + 16 * 4096);
  vc[3] = *(const bf16x8*)(vp + 16 * 4096 + 32);

  int kv = 0, rem = sl;

#pragma unroll 2
  for (int kt = 0; kt < 64; ++kt) {
    // --- prefetch next K/V tile (clamped at the end) ---
    const short* kpn = kp + ((kt < 63) ? 64 * 32 : 0);
    const short* vpn = vp + ((kt < 63) ? 64 : 0);
    bf16x8 kn[4], vn[4];
#pragma unroll
    for (int t4 = 0; t4 < 4; ++t4) kn[t4] = *(const bf16x8*)(kpn + t4 * 512);
    vn[0] = *(const bf16x8*)(vpn);
    vn[1] = *(const bf16x8*)(vpn + 32);
    vn[2] = *(const bf16x8*)(vpn + 16 * 4096);
    vn[3] = *(const bf16x8*)(vpn + 16 * 4096 + 32);

    // --- S^T = K . Q^T : lane holds 4 consecutive keys for q-row l15 ---
    f32x4 S[2][4];
#pragma unroll
    for (int g = 0; g < 2; ++g)
#pragma unroll
      for (int t4 = 0; t4 < 4; ++t4)
        S[g][t4] = __builtin_amdgcn_mfma_f32_16x16x32_bf16(kc[t4], qf[g], fz, 0, 0, 0);

    // --- bias + exp2 + pack + P write ---
    const int kb0 = kt * 64;
    if (rem >= 64) {            // whole tile in one variate (always, for sl%64==0)
      float lb[2];
      lb[0] = (qv[0] == kv) ? lbs : lbd;
      lb[1] = (qv[1] == kv) ? lbs : lbd;
#pragma unroll
      for (int g = 0; g < 2; ++g)
#pragma unroll
        for (int t4 = 0; t4 < 4; ++t4) {
          float p0 = EXP2(S[g][t4][0] * LOG2E + lb[g]);
          float p1 = EXP2(S[g][t4][1] * LOG2E + lb[g]);
          float p2 = EXP2(S[g][t4][2] * LOG2E + lb[g]);
          float p3 = EXP2(S[g][t4][3] * LOG2E + lb[g]);
          den[g] += (p0 + p1) + (p2 + p3);
          u32x2 u; u.x = cvt_pk_bf16(p0, p1); u.y = cvt_pk_bf16(p2, p3);
          *(u32x2*)(pw + g * 1152 + t4 * 16) = u;
        }
    } else {                    // variate boundary inside tile: range-compare path
#pragma unroll
      for (int g = 0; g < 2; ++g)
#pragma unroll
        for (int t4 = 0; t4 < 4; ++t4) {
          const int gk = kb0 + t4 * 16 + lg * 4;
          float p[4];
#pragma unroll
          for (int j = 0; j < 4; ++j) {
            float lb = ((unsigned)(gk + j - qlo[g]) < (unsigned)sl) ? lbs : lbd;
            p[j] = EXP2(S[g][t4][j] * LOG2E + lb);
            den[g] += p[j];
          }
          u32x2 u; u.x = cvt_pk_bf16(p[0], p[1]); u.y = cvt_pk_bf16(p[2], p[3]);
          *(u32x2*)(pw + g * 1152 + t4 * 16) = u;
        }
    }
    rem -= 64;
    while (rem <= 0) { kv += 1; rem += sl; }

    // --- O += P . V  (A-frag read of P from LDS, same wave) ---
#pragma unroll
    for (int g = 0; g < 2; ++g)
#pragma unroll
      for (int kk = 0; kk < 2; ++kk) {
        bf16x8 pf = *(const bf16x8*)(pr + g * 1152 + kk * 32);
        Oacc[g][0] = __builtin_amdgcn_mfma_f32_16x16x32_bf16(pf, vc[kk],     Oacc[g][0], 0, 0, 0);
        Oacc[g][1] = __builtin_amdgcn_mfma_f32_16x16x32_bf16(pf, vc[2 + kk], Oacc[g][1], 0, 0, 0);
      }

    // --- rotate prefetch registers ---
#pragma unroll
    for (int i = 0; i < 4; ++i) { kc[i] = kn[i]; vc[i] = vn[i]; }
    kp = kpn; vp = vpn;
  }

  // --- den: reduce across the 4 lane-groups holding the same q-row ---
#pragma unroll
  for (int g = 0; g < 2; ++g) {
    den[g] += __shfl_xor(den[g], 16, 64);
    den[g] += __shfl_xor(den[g], 32, 64);
  }

  const int b = bh >> 3;
#pragma unroll
  for (int g = 0; g < 2; ++g)
#pragma unroll
    for (int j = 0; j < 4; ++j) {
      const float dj = __shfl(den[g], lg * 4 + j, 64);
      const float rd = 1.0f / dj;
      const int n = qb + g * 16 + lg * 4 + j;
#pragma unroll
      for (int nt = 0; nt < 2; ++nt) {
        const int col = h * 32 + nt * 16 + l15;
        Ao[((size_t)(b * 4096 + n)) * 256 + col] = Oacc[g][nt][j] * rd;
      }
    }
}

// ---------------------------------------------------------------------------
extern "C" void kernel_launch(void* const* d_in, const int* in_sizes, int n_in,
                              void* d_out, int out_size, void* d_ws, size_t ws_size,
                              hipStream_t stream) {
  (void)in_sizes; (void)n_in; (void)out_size; (void)ws_size;
  const float* hs = (const float*)d_in[0];
  const float* qw = (const float*)d_in[1];
  const float* qb = (const float*)d_in[2];
  const float* kw = (const float*)d_in[3];
  const float* kb = (const float*)d_in[4];
  const float* vw = (const float*)d_in[5];
  const float* vb = (const float*)d_in[6];
  const float* ow = (const float*)d_in[7];
  const float* ob = (const float*)d_in[8];
  const float* ab = (const float*)d_in[9];
  const int* sl   = (const int*)d_in[11];
  float* out = (float*)d_out;

  char* ws = (char*)d_ws;
  float* qkv   = (float*)(ws);                 // 8192*768 f32
  float* attno = (float*)(ws + 25165824);      // 8192*256 f32
  short* Qbf   = (short*)(ws + 33554432);      // 16*4096*32 bf16
  short* Kbf   = (short*)(ws + 37748736);
  short* Vtb   = (short*)(ws + 41943040);      // V transposed

  gemm_xwt<<<dim3(64, 6), 256, 0, stream>>>(hs, qw, kw, vw, qb, kb, vb, qkv, 768);
  rope_pack<<<dim3(12288), 256, 0, stream>>>(qkv, Qbf, Kbf, Vtb);
  attn_fwd<<<dim3(32, 16), 256, 0, stream>>>(Qbf, Kbf, Vtb, ab, sl, attno);
  gemm_xwt<<<dim3(64, 2), 256, 0, stream>>>(attno, ow, ow, ow, ob, ob, ob, out, 256);
}

// Round 3
// 205.682 us; speedup vs baseline: 1.1614x; 1.0021x over previous
//
#include <hip/hip_runtime.h>
#include <cstdint>
#include <cstddef>

typedef __attribute__((ext_vector_type(8))) short bf16x8;
typedef __attribute__((ext_vector_type(4))) float f32x4;
typedef __attribute__((ext_vector_type(2))) unsigned int u32x2;
typedef __attribute__((ext_vector_type(4))) unsigned int u32x4;

extern "C" __device__ float __ocml_native_exp2_f32(float);
#define EXP2 __ocml_native_exp2_f32

__device__ __forceinline__ unsigned cvt_pk_bf16(float a, float b) {
  unsigned r;
  asm("v_cvt_pk_bf16_f32 %0, %1, %2" : "=v"(r) : "v"(a), "v"(b));
  return r;
}

__device__ __forceinline__ short f2bf(float f) {
  unsigned u = __float_as_uint(f);
  u += 0x7FFFu + ((u >> 16) & 1u);
  return (short)(u >> 16);
}

__device__ __forceinline__ float bf2f(short s) {
  return __uint_as_float(((unsigned)(unsigned short)s) << 16);
}

// timescale[r] = 10000^(r/16) = 10^(r/4); these are 1/timescale
__constant__ float INV_TS[8] = {
  1.0f, 0.5623413251903491f, 0.31622776601683794f, 0.17782794100389228f,
  0.1f, 0.05623413251903491f, 0.031622776601683794f, 0.017782794100389228f
};

// ---------------------------------------------------------------------------
// bf16 MFMA GEMM: C[M x Ntot] = X[M x 256] @ W[* x 256]^T + bias.
// A read as f32 (A_BF16=0) or bf16 (A_BF16=1), converted during LDS staging.
// Tile 128x64, BK=32, 256 threads = 4 waves in 2x2 (each 64x32 output).
// Column block of 64 picks W0/W1/W2 (each 256 cols). Grid: (M/128, Ntot/64).
// ---------------------------------------------------------------------------
template<int A_BF16, int OUT_BF16>
__global__ __launch_bounds__(256) void gemm_mfma(
    const void* __restrict__ Ain,
    const float* __restrict__ W0, const float* __restrict__ W1, const float* __restrict__ W2,
    const float* __restrict__ b0, const float* __restrict__ b1, const float* __restrict__ b2,
    void* __restrict__ Cout, int Ntot)
{
  __shared__ short sA[128 * 40];   // [row][k], stride 40 elems (80B)
  __shared__ short sB[64 * 40];
  const int t = threadIdx.x;
  const int w = t >> 6, l = t & 63;
  const int l15 = l & 15, lg = l >> 4;
  const int rbase = blockIdx.x * 128;
  const int cgbase = blockIdx.y * 64;
  const int mat = cgbase >> 8;
  const float* W = (mat == 0) ? W0 : ((mat == 1) ? W1 : W2);
  const float* bias = (mat == 0) ? b0 : ((mat == 1) ? b1 : b2);
  const int wbase = cgbase & 255;

  const int ar = t >> 1, akc = (t & 1) * 16;   // A staging: row, k-offset
  const int br = t >> 2, bkc = (t & 3) * 8;    // B staging: row, k-offset

  const float* Bg = W + (size_t)(wbase + br) * 256 + bkc;
  const float* Agf = (const float*)Ain + (size_t)(rbase + ar) * 256 + akc;
  const short* Agh = (const short*)Ain + (size_t)(rbase + ar) * 256 + akc;

  const int wr = w >> 1, wc = w & 1;

  f32x4 acc[4][2];
#pragma unroll
  for (int i = 0; i < 4; ++i) {
    acc[i][0] = {0.f, 0.f, 0.f, 0.f};
    acc[i][1] = {0.f, 0.f, 0.f, 0.f};
  }

  for (int k0 = 0; k0 < 256; k0 += 32) {
    // global loads (convert to bf16 in-register)
    u32x4 pa0, pa1;
    if constexpr (A_BF16) {
      pa0 = *(const u32x4*)(Agh + k0);
      pa1 = *(const u32x4*)(Agh + k0 + 8);
    } else {
      f32x4 a0 = *(const f32x4*)(Agf + k0);
      f32x4 a1 = *(const f32x4*)(Agf + k0 + 4);
      f32x4 a2 = *(const f32x4*)(Agf + k0 + 8);
      f32x4 a3 = *(const f32x4*)(Agf + k0 + 12);
      pa0.x = cvt_pk_bf16(a0[0], a0[1]); pa0.y = cvt_pk_bf16(a0[2], a0[3]);
      pa0.z = cvt_pk_bf16(a1[0], a1[1]); pa0.w = cvt_pk_bf16(a1[2], a1[3]);
      pa1.x = cvt_pk_bf16(a2[0], a2[1]); pa1.y = cvt_pk_bf16(a2[2], a2[3]);
      pa1.z = cvt_pk_bf16(a3[0], a3[1]); pa1.w = cvt_pk_bf16(a3[2], a3[3]);
    }
    f32x4 bv0 = *(const f32x4*)(Bg + k0);
    f32x4 bv1 = *(const f32x4*)(Bg + k0 + 4);
    u32x4 pb;
    pb.x = cvt_pk_bf16(bv0[0], bv0[1]); pb.y = cvt_pk_bf16(bv0[2], bv0[3]);
    pb.z = cvt_pk_bf16(bv1[0], bv1[1]); pb.w = cvt_pk_bf16(bv1[2], bv1[3]);

    __syncthreads();
    *(u32x4*)(sA + ar * 40 + akc)     = pa0;
    *(u32x4*)(sA + ar * 40 + akc + 8) = pa1;
    *(u32x4*)(sB + br * 40 + bkc)     = pb;
    __syncthreads();

    bf16x8 af[4], bfr[2];
#pragma unroll
    for (int i = 0; i < 4; ++i)
      af[i] = *(const bf16x8*)(sA + (wr * 64 + i * 16 + l15) * 40 + lg * 8);
#pragma unroll
    for (int j = 0; j < 2; ++j)
      bfr[j] = *(const bf16x8*)(sB + (wc * 32 + j * 16 + l15) * 40 + lg * 8);
#pragma unroll
    for (int i = 0; i < 4; ++i)
#pragma unroll
      for (int j = 0; j < 2; ++j)
        acc[i][j] = __builtin_amdgcn_mfma_f32_16x16x32_bf16(af[i], bfr[j], acc[i][j], 0, 0, 0);
  }

#pragma unroll
  for (int i = 0; i < 4; ++i)
#pragma unroll
    for (int j = 0; j < 2; ++j) {
      const int n = cgbase + wc * 32 + j * 16 + l15;
      const float bv = bias[wbase + wc * 32 + j * 16 + l15];
#pragma unroll
      for (int jj = 0; jj < 4; ++jj) {
        const size_t m = (size_t)(rbase + wr * 64 + i * 16 + lg * 4 + jj);
        const float val = acc[i][j][jj] + bv;
        if constexpr (OUT_BF16) ((short*)Cout)[m * Ntot + n] = f2bf(val);
        else                    ((float*)Cout)[m * Ntot + n] = val;
      }
    }
}

// ---------------------------------------------------------------------------
// RoPE + scale + pack. QKV now bf16 [8192][768]. Q,K: [16][4096][32].
// V TRANSPOSED: [16][32][4096].
// ---------------------------------------------------------------------------
__global__ __launch_bounds__(256) void rope_pack(
    const short* __restrict__ QKV,
    short* __restrict__ Qo, short* __restrict__ Ko, short* __restrict__ Vo)
{
  const int id = blockIdx.x * 256 + threadIdx.x;
  const int dh = id & 15;
  const int hh = (id >> 4) & 7;
  const int r7 = id >> 7;
  const int mt = r7 % 3;
  const int row = r7 / 3;
  const int b = row >> 12, n = row & 4095;
  const int bh = b * 8 + hh;
  const short* src = QKV + (size_t)row * 768 + mt * 256 + hh * 32 + dh;
  float v0 = bf2f(src[0]), v1 = bf2f(src[16]);
  if (mt == 0) { v0 *= 0.17677669529663687f; v1 *= 0.17677669529663687f; }
  if (mt < 2) {
    if (dh < 8) {
      float ang = (float)n * INV_TS[dh];
      float s = sinf(ang), c = cosf(ang);
      float r0 = v0 * c - v1 * s;
      float r1 = v1 * c + v0 * s;
      v0 = r0; v1 = r1;
    }
    short* dst = (mt == 0 ? Qo : Ko) + (size_t)bh * 4096 * 32 + n * 32 + dh;
    dst[0]  = f2bf(v0);
    dst[16] = f2bf(v1);
  } else {
    short* dst = Vo + (size_t)bh * 32 * 4096 + (size_t)dh * 4096 + n;
    dst[0]         = f2bf(v0);
    dst[16 * 4096] = f2bf(v1);
  }
}

// ---------------------------------------------------------------------------
// Flash attention v3: barrier-free, S^T orientation, K-split across
// blockIdx.z (2 halves of the key range). Writes UNNORMALIZED partial O and
// partial den. Grid: (4096/128, 16, 2). Block 256 = 4 independent waves.
// ---------------------------------------------------------------------------
__global__ __launch_bounds__(256, 4) void attn_fwd(
    const short* __restrict__ Qg, const short* __restrict__ Kg, const short* __restrict__ Vg,
    const float* __restrict__ ab, const int* __restrict__ slp,
    float* __restrict__ Op, float* __restrict__ denp)
{
  __shared__ short sP[4][32 * 72];   // per-wave P tile [32 q][64 k], stride 72
  const int t = threadIdx.x, w = t >> 6, l = t & 63;
  const int l15 = l & 15, lg = l >> 4;
  const int bh = blockIdx.y, h = bh & 7;
  const int z = blockIdx.z;
  const int qb = blockIdx.x * 128 + w * 32;
  const int sl = *slp;

  const short* Qb = Qg + (size_t)bh * (4096 * 32);
  const short* Kb = Kg + (size_t)bh * (4096 * 32);
  const short* Vb = Vg + (size_t)bh * (32 * 4096);

  bf16x8 qf[2];
  qf[0] = *(const bf16x8*)(Qb + (size_t)(qb + l15) * 32 + lg * 8);
  qf[1] = *(const bf16x8*)(Qb + (size_t)(qb + 16 + l15) * 32 + lg * 8);

  const float LOG2E = 1.4426950408889634f;
  const float lbs = ab[h * 2] * LOG2E, lbd = ab[h * 2 + 1] * LOG2E;
  const int qrow[2] = { qb + l15, qb + 16 + l15 };
  const int qv[2]   = { qrow[0] / sl, qrow[1] / sl };
  const int qlo[2]  = { qv[0] * sl, qv[1] * sl };

  short* P = &sP[w][0];
  short* pw = P + l15 * 72 + lg * 4;
  const short* pr = P + l15 * 72 + lg * 8;

  const f32x4 fz = {0.f, 0.f, 0.f, 0.f};
  f32x4 Oacc[2][2];
  Oacc[0][0] = fz; Oacc[0][1] = fz; Oacc[1][0] = fz; Oacc[1][1] = fz;
  float den[2] = {0.f, 0.f};

  const int kt0 = z * 32, kt1 = kt0 + 32;
  const int kstart = kt0 * 64;

  const short* kp = Kb + (size_t)(kstart + l15) * 32 + lg * 8;
  const short* vp = Vb + (size_t)l15 * 4096 + kstart + lg * 8;

  bf16x8 kc[4], vc[4];
#pragma unroll
  for (int t4 = 0; t4 < 4; ++t4) kc[t4] = *(const bf16x8*)(kp + t4 * 512);
  vc[0] = *(const bf16x8*)(vp);
  vc[1] = *(const bf16x8*)(vp + 32);
  vc[2] = *(const bf16x8*)(vp + 16 * 4096);
  vc[3] = *(const bf16x8*)(vp + 16 * 4096 + 32);

  int kv = kstart / sl;
  int rem = (kv + 1) * sl - kstart;

#pragma unroll 2
  for (int kt = kt0; kt < kt1; ++kt) {
    const short* kpn = kp + ((kt < kt1 - 1) ? 64 * 32 : 0);
    const short* vpn = vp + ((kt < kt1 - 1) ? 64 : 0);
    bf16x8 kn[4], vn[4];
#pragma unroll
    for (int t4 = 0; t4 < 4; ++t4) kn[t4] = *(const bf16x8*)(kpn + t4 * 512);
    vn[0] = *(const bf16x8*)(vpn);
    vn[1] = *(const bf16x8*)(vpn + 32);
    vn[2] = *(const bf16x8*)(vpn + 16 * 4096);
    vn[3] = *(const bf16x8*)(vpn + 16 * 4096 + 32);

    // S^T = K . Q^T
    f32x4 S[2][4];
#pragma unroll
    for (int g = 0; g < 2; ++g)
#pragma unroll
      for (int t4 = 0; t4 < 4; ++t4)
        S[g][t4] = __builtin_amdgcn_mfma_f32_16x16x32_bf16(kc[t4], qf[g], fz, 0, 0, 0);

    const int kb0 = kt * 64;
    if (rem >= 64) {
      float lb[2];
      lb[0] = (qv[0] == kv) ? lbs : lbd;
      lb[1] = (qv[1] == kv) ? lbs : lbd;
#pragma unroll
      for (int g = 0; g < 2; ++g)
#pragma unroll
        for (int t4 = 0; t4 < 4; ++t4) {
          float p0 = EXP2(S[g][t4][0] * LOG2E + lb[g]);
          float p1 = EXP2(S[g][t4][1] * LOG2E + lb[g]);
          float p2 = EXP2(S[g][t4][2] * LOG2E + lb[g]);
          float p3 = EXP2(S[g][t4][3] * LOG2E + lb[g]);
          den[g] += (p0 + p1) + (p2 + p3);
          u32x2 u; u.x = cvt_pk_bf16(p0, p1); u.y = cvt_pk_bf16(p2, p3);
          *(u32x2*)(pw + g * 1152 + t4 * 16) = u;
        }
    } else {
#pragma unroll
      for (int g = 0; g < 2; ++g)
#pragma unroll
        for (int t4 = 0; t4 < 4; ++t4) {
          const int gk = kb0 + t4 * 16 + lg * 4;
          float p[4];
#pragma unroll
          for (int j = 0; j < 4; ++j) {
            float lb = ((unsigned)(gk + j - qlo[g]) < (unsigned)sl) ? lbs : lbd;
            p[j] = EXP2(S[g][t4][j] * LOG2E + lb);
            den[g] += p[j];
          }
          u32x2 u; u.x = cvt_pk_bf16(p[0], p[1]); u.y = cvt_pk_bf16(p[2], p[3]);
          *(u32x2*)(pw + g * 1152 + t4 * 16) = u;
        }
    }
    rem -= 64;
    while (rem <= 0) { kv += 1; rem += sl; }

    // O += P . V
#pragma unroll
    for (int g = 0; g < 2; ++g)
#pragma unroll
      for (int kk = 0; kk < 2; ++kk) {
        bf16x8 pf = *(const bf16x8*)(pr + g * 1152 + kk * 32);
        Oacc[g][0] = __builtin_amdgcn_mfma_f32_16x16x32_bf16(pf, vc[kk],     Oacc[g][0], 0, 0, 0);
        Oacc[g][1] = __builtin_amdgcn_mfma_f32_16x16x32_bf16(pf, vc[2 + kk], Oacc[g][1], 0, 0, 0);
      }

#pragma unroll
    for (int i = 0; i < 4; ++i) { kc[i] = kn[i]; vc[i] = vn[i]; }
    kp = kpn; vp = vpn;
  }

  // reduce den across lg groups (lanes with same l15)
#pragma unroll
  for (int g = 0; g < 2; ++g) {
    den[g] += __shfl_xor(den[g], 16, 64);
    den[g] += __shfl_xor(den[g], 32, 64);
  }

  const size_t zb = ((size_t)z * 16 + bh) * 4096;
  if (lg == 0) {
#pragma unroll
    for (int g = 0; g < 2; ++g)
      denp[zb + qb + g * 16 + l15] = den[g];
  }
#pragma unroll
  for (int g = 0; g < 2; ++g)
#pragma unroll
    for (int nt = 0; nt < 2; ++nt)
#pragma unroll
      for (int j = 0; j < 4; ++j) {
        const int n = qb + g * 16 + lg * 4 + j;
        Op[(zb + n) * 32 + nt * 16 + l15] = Oacc[g][nt][j];
      }
}

// ---------------------------------------------------------------------------
// Combine K-split partials: attno[b][n][h*32+d] = (O0+O1)/(d0+d1) as bf16.
// ---------------------------------------------------------------------------
__global__ __launch_bounds__(256) void combine(
    const float* __restrict__ Op, const float* __restrict__ denp,
    short* __restrict__ attno)
{
  const int id = blockIdx.x * 256 + threadIdx.x;   // 16*4096*8
  const int d4 = (id & 7) * 4;
  const int n  = (id >> 3) & 4095;
  const int bh = id >> 15;
  const size_t base = ((size_t)bh * 4096 + n) * 32 + d4;
  const size_t zoff = (size_t)16 * 4096 * 32;
  f32x4 o0 = *(const f32x4*)(Op + base);
  f32x4 o1 = *(const f32x4*)(Op + zoff + base);
  const float rd = 1.0f / (denp[bh * 4096 + n] + denp[16 * 4096 + bh * 4096 + n]);
  const int b = bh >> 3, hh = bh & 7;
  u32x2 u;
  u.x = cvt_pk_bf16((o0[0] + o1[0]) * rd, (o0[1] + o1[1]) * rd);
  u.y = cvt_pk_bf16((o0[2] + o1[2]) * rd, (o0[3] + o1[3]) * rd);
  *(u32x2*)(attno + ((size_t)(b * 4096 + n) * 256 + hh * 32 + d4)) = u;
}

// ---------------------------------------------------------------------------
extern "C" void kernel_launch(void* const* d_in, const int* in_sizes, int n_in,
                              void* d_out, int out_size, void* d_ws, size_t ws_size,
                              hipStream_t stream) {
  (void)in_sizes; (void)n_in; (void)out_size; (void)ws_size;
  const float* hs = (const float*)d_in[0];
  const float* qw = (const float*)d_in[1];
  const float* qb = (const float*)d_in[2];
  const float* kw = (const float*)d_in[3];
  const float* kb = (const float*)d_in[4];
  const float* vw = (const float*)d_in[5];
  const float* vb = (const float*)d_in[6];
  const float* ow = (const float*)d_in[7];
  const float* ob = (const float*)d_in[8];
  const float* ab = (const float*)d_in[9];
  const int* sl   = (const int*)d_in[11];
  float* out = (float*)d_out;

  char* ws = (char*)d_ws;
  // region A [0, 16.78MB): qkv bf16 (dead after rope_pack), then Op overlays
  short* qkvb = (short*)(ws);                    // 8192*768*2 = 12,582,912
  float* Op   = (float*)(ws);                    // 2*16*4096*32*4 = 16,777,216
  short* Qbf  = (short*)(ws + 16777216);         // 4,194,304
  short* Kbf  = (short*)(ws + 20971520);         // 4,194,304
  short* Vtb  = (short*)(ws + 25165824);         // 4,194,304
  float* denp = (float*)(ws + 29360128);         // 2*16*4096*4 = 524,288
  short* attno= (short*)(ws + 29884416);         // 8192*256*2 = 4,194,304

  // QKV projection (bf16 MFMA, f32 inputs converted in staging) -> bf16 qkv
  gemm_mfma<0, 1><<<dim3(64, 12), 256, 0, stream>>>(hs, qw, kw, vw, qb, kb, vb, qkvb, 768);
  // RoPE + scale + bf16 pack (V transposed)
  rope_pack<<<dim3(12288), 256, 0, stream>>>(qkvb, Qbf, Kbf, Vtb);
  // attention, K-split in 2 (partial unnormalized O + den)
  attn_fwd<<<dim3(32, 16, 2), 256, 0, stream>>>(Qbf, Kbf, Vtb, ab, sl, Op, denp);
  // merge partials -> bf16 attention output
  combine<<<dim3(2048), 256, 0, stream>>>(Op, denp, attno);
  // output projection (bf16 MFMA) -> f32
  gemm_mfma<1, 0><<<dim3(64, 4), 256, 0, stream>>>(attno, ow, ow, ow, ob, ob, ob, out, 256);
}

// Round 4
// 109.164 us; speedup vs baseline: 2.1883x; 1.8841x over previous
//
#include <hip/hip_runtime.h>
#include <cstdint>
#include <cstddef>

typedef __attribute__((ext_vector_type(8))) short bf16x8;
typedef __attribute__((ext_vector_type(4))) float f32x4;
typedef __attribute__((ext_vector_type(2))) unsigned int u32x2;
typedef __attribute__((ext_vector_type(4))) unsigned int u32x4;

extern "C" __device__ float __ocml_native_exp2_f32(float);
#define EXP2 __ocml_native_exp2_f32

__device__ __forceinline__ unsigned cvt_pk_bf16(float a, float b) {
  unsigned r;
  asm("v_cvt_pk_bf16_f32 %0, %1, %2" : "=v"(r) : "v"(a), "v"(b));
  return r;
}

__device__ __forceinline__ short f2bf(float f) {
  unsigned u = __float_as_uint(f);
  u += 0x7FFFu + ((u >> 16) & 1u);
  return (short)(u >> 16);
}

__device__ __forceinline__ float bf2f(short s) {
  return __uint_as_float(((unsigned)(unsigned short)s) << 16);
}

// timescale[r] = 10000^(r/16) = 10^(r/4); these are 1/timescale
__constant__ float INV_TS[8] = {
  1.0f, 0.5623413251903491f, 0.31622776601683794f, 0.17782794100389228f,
  0.1f, 0.05623413251903491f, 0.031622776601683794f, 0.017782794100389228f
};

// ---------------------------------------------------------------------------
// bf16 MFMA GEMM: C[M x Ntot] = X[M x 256] @ W[* x 256]^T + bias.
// Tile 128x64, BK=32, 256 threads = 4 waves (2x2). Grid: (M/128, Ntot/64).
// ---------------------------------------------------------------------------
template<int A_BF16, int OUT_BF16>
__global__ __launch_bounds__(256) void gemm_mfma(
    const void* __restrict__ Ain,
    const float* __restrict__ W0, const float* __restrict__ W1, const float* __restrict__ W2,
    const float* __restrict__ b0, const float* __restrict__ b1, const float* __restrict__ b2,
    void* __restrict__ Cout, int Ntot)
{
  __shared__ short sA[128 * 40];
  __shared__ short sB[64 * 40];
  const int t = threadIdx.x;
  const int w = t >> 6, l = t & 63;
  const int l15 = l & 15, lg = l >> 4;
  const int rbase = blockIdx.x * 128;
  const int cgbase = blockIdx.y * 64;
  const int mat = cgbase >> 8;
  const float* W = (mat == 0) ? W0 : ((mat == 1) ? W1 : W2);
  const float* bias = (mat == 0) ? b0 : ((mat == 1) ? b1 : b2);
  const int wbase = cgbase & 255;

  const int ar = t >> 1, akc = (t & 1) * 16;
  const int br = t >> 2, bkc = (t & 3) * 8;

  const float* Bg = W + (size_t)(wbase + br) * 256 + bkc;
  const float* Agf = (const float*)Ain + (size_t)(rbase + ar) * 256 + akc;
  const short* Agh = (const short*)Ain + (size_t)(rbase + ar) * 256 + akc;

  const int wr = w >> 1, wc = w & 1;

  f32x4 acc[4][2];
#pragma unroll
  for (int i = 0; i < 4; ++i) {
    acc[i][0] = {0.f, 0.f, 0.f, 0.f};
    acc[i][1] = {0.f, 0.f, 0.f, 0.f};
  }

  for (int k0 = 0; k0 < 256; k0 += 32) {
    u32x4 pa0, pa1;
    if constexpr (A_BF16) {
      pa0 = *(const u32x4*)(Agh + k0);
      pa1 = *(const u32x4*)(Agh + k0 + 8);
    } else {
      f32x4 a0 = *(const f32x4*)(Agf + k0);
      f32x4 a1 = *(const f32x4*)(Agf + k0 + 4);
      f32x4 a2 = *(const f32x4*)(Agf + k0 + 8);
      f32x4 a3 = *(const f32x4*)(Agf + k0 + 12);
      pa0.x = cvt_pk_bf16(a0[0], a0[1]); pa0.y = cvt_pk_bf16(a0[2], a0[3]);
      pa0.z = cvt_pk_bf16(a1[0], a1[1]); pa0.w = cvt_pk_bf16(a1[2], a1[3]);
      pa1.x = cvt_pk_bf16(a2[0], a2[1]); pa1.y = cvt_pk_bf16(a2[2], a2[3]);
      pa1.z = cvt_pk_bf16(a3[0], a3[1]); pa1.w = cvt_pk_bf16(a3[2], a3[3]);
    }
    f32x4 bv0 = *(const f32x4*)(Bg + k0);
    f32x4 bv1 = *(const f32x4*)(Bg + k0 + 4);
    u32x4 pb;
    pb.x = cvt_pk_bf16(bv0[0], bv0[1]); pb.y = cvt_pk_bf16(bv0[2], bv0[3]);
    pb.z = cvt_pk_bf16(bv1[0], bv1[1]); pb.w = cvt_pk_bf16(bv1[2], bv1[3]);

    __syncthreads();
    *(u32x4*)(sA + ar * 40 + akc)     = pa0;
    *(u32x4*)(sA + ar * 40 + akc + 8) = pa1;
    *(u32x4*)(sB + br * 40 + bkc)     = pb;
    __syncthreads();

    bf16x8 af[4], bfr[2];
#pragma unroll
    for (int i = 0; i < 4; ++i)
      af[i] = *(const bf16x8*)(sA + (wr * 64 + i * 16 + l15) * 40 + lg * 8);
#pragma unroll
    for (int j = 0; j < 2; ++j)
      bfr[j] = *(const bf16x8*)(sB + (wc * 32 + j * 16 + l15) * 40 + lg * 8);
#pragma unroll
    for (int i = 0; i < 4; ++i)
#pragma unroll
      for (int j = 0; j < 2; ++j)
        acc[i][j] = __builtin_amdgcn_mfma_f32_16x16x32_bf16(af[i], bfr[j], acc[i][j], 0, 0, 0);
  }

#pragma unroll
  for (int i = 0; i < 4; ++i)
#pragma unroll
    for (int j = 0; j < 2; ++j) {
      const int n = cgbase + wc * 32 + j * 16 + l15;
      const float bv = bias[wbase + wc * 32 + j * 16 + l15];
#pragma unroll
      for (int jj = 0; jj < 4; ++jj) {
        const size_t m = (size_t)(rbase + wr * 64 + i * 16 + lg * 4 + jj);
        const float val = acc[i][j][jj] + bv;
        if constexpr (OUT_BF16) ((short*)Cout)[m * Ntot + n] = f2bf(val);
        else                    ((float*)Cout)[m * Ntot + n] = val;
      }
    }
}

// ---------------------------------------------------------------------------
// RoPE + scale + pack. QKV bf16 [8192][768]. Q,K: [16][4096][32].
// V TRANSPOSED: [16][32][4096].
// ---------------------------------------------------------------------------
__global__ __launch_bounds__(256) void rope_pack(
    const short* __restrict__ QKV,
    short* __restrict__ Qo, short* __restrict__ Ko, short* __restrict__ Vo)
{
  const int id = blockIdx.x * 256 + threadIdx.x;
  const int dh = id & 15;
  const int hh = (id >> 4) & 7;
  const int r7 = id >> 7;
  const int mt = r7 % 3;
  const int row = r7 / 3;
  const int b = row >> 12, n = row & 4095;
  const int bh = b * 8 + hh;
  const short* src = QKV + (size_t)row * 768 + mt * 256 + hh * 32 + dh;
  float v0 = bf2f(src[0]), v1 = bf2f(src[16]);
  if (mt == 0) { v0 *= 0.17677669529663687f; v1 *= 0.17677669529663687f; }
  if (mt < 2) {
    if (dh < 8) {
      float ang = (float)n * INV_TS[dh];
      float s = sinf(ang), c = cosf(ang);
      float r0 = v0 * c - v1 * s;
      float r1 = v1 * c + v0 * s;
      v0 = r0; v1 = r1;
    }
    short* dst = (mt == 0 ? Qo : Ko) + (size_t)bh * 4096 * 32 + n * 32 + dh;
    dst[0]  = f2bf(v0);
    dst[16] = f2bf(v1);
  } else {
    short* dst = Vo + (size_t)bh * 32 * 4096 + (size_t)dh * 4096 + n;
    dst[0]         = f2bf(v0);
    dst[16 * 4096] = f2bf(v1);
  }
}

// ---------------------------------------------------------------------------
// Flash attention v4: LDS-shared K/V (double-buffered, single barrier/iter),
// S^T orientation, per-wave P in LDS, K-split across blockIdx.z.
// Block 256 = 4 waves, each owning 32 q-rows. Grid: (4096/128, 16, 2).
// Writes UNNORMALIZED partial O and partial den.
// ---------------------------------------------------------------------------
__global__ __launch_bounds__(256, 4) void attn_fwd(
    const short* __restrict__ Qg, const short* __restrict__ Kg, const short* __restrict__ Vg,
    const float* __restrict__ ab, const int* __restrict__ slp,
    float* __restrict__ Op, float* __restrict__ denp)
{
  __shared__ short sK[2][64 * 40];   // [key][dim], stride 40
  __shared__ short sV[2][32 * 72];   // [dim][key], stride 72
  __shared__ short sP[4][32 * 72];   // per-wave P [32 q][64 k], stride 72
  const int t = threadIdx.x, w = t >> 6, l = t & 63;
  const int l15 = l & 15, lg = l >> 4;
  const int bh = blockIdx.y, h = bh & 7;
  const int z = blockIdx.z;
  const int qb = blockIdx.x * 128 + w * 32;
  const int sl = *slp;

  const short* Qb = Qg + (size_t)bh * (4096 * 32);
  const short* Kb = Kg + (size_t)bh * (4096 * 32);
  const short* Vb = Vg + (size_t)bh * (32 * 4096);

  bf16x8 qf[2];
  qf[0] = *(const bf16x8*)(Qb + (size_t)(qb + l15) * 32 + lg * 8);
  qf[1] = *(const bf16x8*)(Qb + (size_t)(qb + 16 + l15) * 32 + lg * 8);

  const float LOG2E = 1.4426950408889634f;
  const float lbs = ab[h * 2] * LOG2E, lbd = ab[h * 2 + 1] * LOG2E;
  const int qv[2]  = { (qb + l15) / sl, (qb + 16 + l15) / sl };
  const int qlo[2] = { qv[0] * sl, qv[1] * sl };

  short* P = &sP[w][0];
  short* pw = P + l15 * 72 + lg * 4;
  const short* pr = P + l15 * 72 + lg * 8;

  const f32x4 fz = {0.f, 0.f, 0.f, 0.f};
  f32x4 Oacc[2][2];
  Oacc[0][0] = fz; Oacc[0][1] = fz; Oacc[1][0] = fz; Oacc[1][1] = fz;
  float den[2] = {0.f, 0.f};

  const int kt0 = z * 32, kt1 = kt0 + 32;
  const int kstart = kt0 * 64;

  // staging assignments (whole block cooperates)
  const int kr = t >> 2, kc0 = (t & 3) * 8;   // K: row 0..63, 8-dim chunk
  const int vd = t >> 3, vk0 = (t & 7) * 8;   // V: dim 0..31, 8-key chunk
  const short* kg = Kb + (size_t)(kstart + kr) * 32 + kc0;
  const short* vg = Vb + (size_t)vd * 4096 + kstart + vk0;

  // prologue: tile kt0 -> buf0; prefetch kt0+1 into regs
  bf16x8 krg = *(const bf16x8*)kg;
  bf16x8 vrg = *(const bf16x8*)vg;
  *(bf16x8*)(&sK[0][0] + kr * 40 + kc0) = krg;
  *(bf16x8*)(&sV[0][0] + vd * 72 + vk0) = vrg;
  kg += 64 * 32; vg += 64;
  krg = *(const bf16x8*)kg;
  vrg = *(const bf16x8*)vg;
  __syncthreads();

  int kv = kstart / sl;
  int rem = (kv + 1) * sl - kstart;
  int cur = 0;

#pragma unroll 2
  for (int kt = kt0; kt < kt1; ++kt) {
    // 1) park tile kt+1 (loaded last iter) into buf[cur^1]; nobody reads it this iter
    *(bf16x8*)(&sK[cur ^ 1][0] + kr * 40 + kc0) = krg;
    *(bf16x8*)(&sV[cur ^ 1][0] + vd * 72 + vk0) = vrg;
    // 2) issue global loads for tile kt+2 (latency hides under compute)
    const int adv = (kt + 2 < kt1) ? 1 : 0;
    kg += adv * (64 * 32); vg += adv * 64;
    krg = *(const bf16x8*)kg;
    vrg = *(const bf16x8*)vg;

    // 3) compute from buf[cur]
    const short* sKc = &sK[cur][0];
    const short* sVc = &sV[cur][0];

    f32x4 S[2][4];
#pragma unroll
    for (int t4 = 0; t4 < 4; ++t4) {
      bf16x8 kf = *(const bf16x8*)(sKc + (t4 * 16 + l15) * 40 + lg * 8);
      S[0][t4] = __builtin_amdgcn_mfma_f32_16x16x32_bf16(kf, qf[0], fz, 0, 0, 0);
      S[1][t4] = __builtin_amdgcn_mfma_f32_16x16x32_bf16(kf, qf[1], fz, 0, 0, 0);
    }

    const int kb0 = kt * 64;
    if (rem >= 64) {
      float lb[2];
      lb[0] = (qv[0] == kv) ? lbs : lbd;
      lb[1] = (qv[1] == kv) ? lbs : lbd;
#pragma unroll
      for (int g = 0; g < 2; ++g)
#pragma unroll
        for (int t4 = 0; t4 < 4; ++t4) {
          float p0 = EXP2(S[g][t4][0] * LOG2E + lb[g]);
          float p1 = EXP2(S[g][t4][1] * LOG2E + lb[g]);
          float p2 = EXP2(S[g][t4][2] * LOG2E + lb[g]);
          float p3 = EXP2(S[g][t4][3] * LOG2E + lb[g]);
          den[g] += (p0 + p1) + (p2 + p3);
          u32x2 u; u.x = cvt_pk_bf16(p0, p1); u.y = cvt_pk_bf16(p2, p3);
          *(u32x2*)(pw + g * 1152 + t4 * 16) = u;
        }
    } else {
#pragma unroll
      for (int g = 0; g < 2; ++g)
#pragma unroll
        for (int t4 = 0; t4 < 4; ++t4) {
          const int gk = kb0 + t4 * 16 + lg * 4;
          float p[4];
#pragma unroll
          for (int j = 0; j < 4; ++j) {
            float lb = ((unsigned)(gk + j - qlo[g]) < (unsigned)sl) ? lbs : lbd;
            p[j] = EXP2(S[g][t4][j] * LOG2E + lb);
            den[g] += p[j];
          }
          u32x2 u; u.x = cvt_pk_bf16(p[0], p[1]); u.y = cvt_pk_bf16(p[2], p[3]);
          *(u32x2*)(pw + g * 1152 + t4 * 16) = u;
        }
    }
    rem -= 64;
    while (rem <= 0) { kv += 1; rem += sl; }

    // O += P . V
#pragma unroll
    for (int g = 0; g < 2; ++g)
#pragma unroll
      for (int kk = 0; kk < 2; ++kk) {
        bf16x8 pf = *(const bf16x8*)(pr + g * 1152 + kk * 32);
        bf16x8 vf0 = *(const bf16x8*)(sVc + l15 * 72 + kk * 32 + lg * 8);
        bf16x8 vf1 = *(const bf16x8*)(sVc + (16 + l15) * 72 + kk * 32 + lg * 8);
        Oacc[g][0] = __builtin_amdgcn_mfma_f32_16x16x32_bf16(pf, vf0, Oacc[g][0], 0, 0, 0);
        Oacc[g][1] = __builtin_amdgcn_mfma_f32_16x16x32_bf16(pf, vf1, Oacc[g][1], 0, 0, 0);
      }

    __syncthreads();
    cur ^= 1;
  }

  // reduce den across lg groups (lanes with same l15)
#pragma unroll
  for (int g = 0; g < 2; ++g) {
    den[g] += __shfl_xor(den[g], 16, 64);
    den[g] += __shfl_xor(den[g], 32, 64);
  }

  const size_t zb = ((size_t)z * 16 + bh) * 4096;
  if (lg == 0) {
#pragma unroll
    for (int g = 0; g < 2; ++g)
      denp[zb + qb + g * 16 + l15] = den[g];
  }
#pragma unroll
  for (int g = 0; g < 2; ++g)
#pragma unroll
    for (int nt = 0; nt < 2; ++nt)
#pragma unroll
      for (int j = 0; j < 4; ++j) {
        const int n = qb + g * 16 + lg * 4 + j;
        Op[(zb + n) * 32 + nt * 16 + l15] = Oacc[g][nt][j];
      }
}

// ---------------------------------------------------------------------------
// Combine K-split partials: attno[b][n][h*32+d] = (O0+O1)/(d0+d1) as bf16.
// ---------------------------------------------------------------------------
__global__ __launch_bounds__(256) void combine(
    const float* __restrict__ Op, const float* __restrict__ denp,
    short* __restrict__ attno)
{
  const int id = blockIdx.x * 256 + threadIdx.x;   // 16*4096*8
  const int d4 = (id & 7) * 4;
  const int n  = (id >> 3) & 4095;
  const int bh = id >> 15;
  const size_t base = ((size_t)bh * 4096 + n) * 32 + d4;
  const size_t zoff = (size_t)16 * 4096 * 32;
  f32x4 o0 = *(const f32x4*)(Op + base);
  f32x4 o1 = *(const f32x4*)(Op + zoff + base);
  const float rd = 1.0f / (denp[bh * 4096 + n] + denp[16 * 4096 + bh * 4096 + n]);
  const int b = bh >> 3, hh = bh & 7;
  u32x2 u;
  u.x = cvt_pk_bf16((o0[0] + o1[0]) * rd, (o0[1] + o1[1]) * rd);
  u.y = cvt_pk_bf16((o0[2] + o1[2]) * rd, (o0[3] + o1[3]) * rd);
  *(u32x2*)(attno + ((size_t)(b * 4096 + n) * 256 + hh * 32 + d4)) = u;
}

// ---------------------------------------------------------------------------
extern "C" void kernel_launch(void* const* d_in, const int* in_sizes, int n_in,
                              void* d_out, int out_size, void* d_ws, size_t ws_size,
                              hipStream_t stream) {
  (void)in_sizes; (void)n_in; (void)out_size; (void)ws_size;
  const float* hs = (const float*)d_in[0];
  const float* qw = (const float*)d_in[1];
  const float* qb = (const float*)d_in[2];
  const float* kw = (const float*)d_in[3];
  const float* kb = (const float*)d_in[4];
  const float* vw = (const float*)d_in[5];
  const float* vb = (const float*)d_in[6];
  const float* ow = (const float*)d_in[7];
  const float* ob = (const float*)d_in[8];
  const float* ab = (const float*)d_in[9];
  const int* sl   = (const int*)d_in[11];
  float* out = (float*)d_out;

  char* ws = (char*)d_ws;
  short* qkvb = (short*)(ws);                    // 8192*768*2 (dead after rope_pack)
  float* Op   = (float*)(ws);                    // 2*16*4096*32*4 = 16,777,216 (overlays qkvb)
  short* Qbf  = (short*)(ws + 16777216);         // 4,194,304
  short* Kbf  = (short*)(ws + 20971520);         // 4,194,304
  short* Vtb  = (short*)(ws + 25165824);         // 4,194,304
  float* denp = (float*)(ws + 29360128);         // 524,288
  short* attno= (short*)(ws + 29884416);         // 4,194,304

  gemm_mfma<0, 1><<<dim3(64, 12), 256, 0, stream>>>(hs, qw, kw, vw, qb, kb, vb, qkvb, 768);
  rope_pack<<<dim3(12288), 256, 0, stream>>>(qkvb, Qbf, Kbf, Vtb);
  attn_fwd<<<dim3(32, 16, 2), 256, 0, stream>>>(Qbf, Kbf, Vtb, ab, sl, Op, denp);
  combine<<<dim3(2048), 256, 0, stream>>>(Op, denp, attno);
  gemm_mfma<1, 0><<<dim3(64, 4), 256, 0, stream>>>(attno, ow, ow, ow, ob, ob, ob, out, 256);
}

// Round 6
// 94.564 us; speedup vs baseline: 2.5262x; 1.1544x over previous
//
#include <hip/hip_runtime.h>
#include <cstdint>
#include <cstddef>

typedef __attribute__((ext_vector_type(8))) short bf16x8;
typedef __attribute__((ext_vector_type(4))) short short4v;
typedef __attribute__((ext_vector_type(4))) float f32x4;
typedef __attribute__((ext_vector_type(2))) unsigned int u32x2;
typedef __attribute__((ext_vector_type(4))) unsigned int u32x4;

extern "C" __device__ float __ocml_native_exp2_f32(float);
#define EXP2 __ocml_native_exp2_f32

__device__ __forceinline__ unsigned cvt_pk_bf16(float a, float b) {
  unsigned r;
  asm("v_cvt_pk_bf16_f32 %0, %1, %2" : "=v"(r) : "v"(a), "v"(b));
  return r;
}

__device__ __forceinline__ short f2bf(float f) {
  unsigned u = __float_as_uint(f);
  u += 0x7FFFu + ((u >> 16) & 1u);
  return (short)(u >> 16);
}

// timescale[r] = 10000^(r/16) = 10^(r/4); these are 1/timescale
__constant__ float INV_TS[8] = {
  1.0f, 0.5623413251903491f, 0.31622776601683794f, 0.17782794100389228f,
  0.1f, 0.05623413251903491f, 0.031622776601683794f, 0.017782794100389228f
};

// ---------------------------------------------------------------------------
// QKV GEMM with FUSED rope + scale + bf16 pack + V transpose in the epilogue.
// C = X[8192x256] @ W[*x256]^T + bias, tile 128x64, 4 waves (2x2).
// mat 0 (q): scale by hd^-0.5, rope, -> Qo[bh][n][32]
// mat 1 (k): rope -> Ko[bh][n][32]
// mat 2 (v): -> Vt[bh][32][n] (transposed, packed 8B stores)
// Grid: (64, 12).  [THE ONLY NEW COMPONENT THIS ROUND — bisect target]
// ---------------------------------------------------------------------------
__global__ __launch_bounds__(256) void gemm_qkv_rope(
    const float* __restrict__ X,
    const float* __restrict__ W0, const float* __restrict__ W1, const float* __restrict__ W2,
    const float* __restrict__ b0, const float* __restrict__ b1, const float* __restrict__ b2,
    short* __restrict__ Qo, short* __restrict__ Ko, short* __restrict__ Vt)
{
  __shared__ short sA[128 * 40];
  __shared__ short sB[64 * 40];
  const int t = threadIdx.x;
  const int w = t >> 6, l = t & 63;
  const int l15 = l & 15, lg = l >> 4;
  const int rbase = blockIdx.x * 128;
  const int cgbase = blockIdx.y * 64;
  const int mat = cgbase >> 8;
  const float* W = (mat == 0) ? W0 : ((mat == 1) ? W1 : W2);
  const float* bias = (mat == 0) ? b0 : ((mat == 1) ? b1 : b2);
  const int wbase = cgbase & 255;

  const int ar = t >> 1, akc = (t & 1) * 16;
  const int br = t >> 2, bkc = (t & 3) * 8;

  const float* Bg = W + (size_t)(wbase + br) * 256 + bkc;
  const float* Agf = X + (size_t)(rbase + ar) * 256 + akc;

  const int wr = w >> 1, wc = w & 1;

  f32x4 acc[4][2];
#pragma unroll
  for (int i = 0; i < 4; ++i) {
    acc[i][0] = {0.f, 0.f, 0.f, 0.f};
    acc[i][1] = {0.f, 0.f, 0.f, 0.f};
  }

  for (int k0 = 0; k0 < 256; k0 += 32) {
    f32x4 a0 = *(const f32x4*)(Agf + k0);
    f32x4 a1 = *(const f32x4*)(Agf + k0 + 4);
    f32x4 a2 = *(const f32x4*)(Agf + k0 + 8);
    f32x4 a3 = *(const f32x4*)(Agf + k0 + 12);
    u32x4 pa0, pa1;
    pa0.x = cvt_pk_bf16(a0[0], a0[1]); pa0.y = cvt_pk_bf16(a0[2], a0[3]);
    pa0.z = cvt_pk_bf16(a1[0], a1[1]); pa0.w = cvt_pk_bf16(a1[2], a1[3]);
    pa1.x = cvt_pk_bf16(a2[0], a2[1]); pa1.y = cvt_pk_bf16(a2[2], a2[3]);
    pa1.z = cvt_pk_bf16(a3[0], a3[1]); pa1.w = cvt_pk_bf16(a3[2], a3[3]);
    f32x4 bv0 = *(const f32x4*)(Bg + k0);
    f32x4 bv1 = *(const f32x4*)(Bg + k0 + 4);
    u32x4 pb;
    pb.x = cvt_pk_bf16(bv0[0], bv0[1]); pb.y = cvt_pk_bf16(bv0[2], bv0[3]);
    pb.z = cvt_pk_bf16(bv1[0], bv1[1]); pb.w = cvt_pk_bf16(bv1[2], bv1[3]);

    __syncthreads();
    *(u32x4*)(sA + ar * 40 + akc)     = pa0;
    *(u32x4*)(sA + ar * 40 + akc + 8) = pa1;
    *(u32x4*)(sB + br * 40 + bkc)     = pb;
    __syncthreads();

    bf16x8 af[4], bfr[2];
#pragma unroll
    for (int i = 0; i < 4; ++i)
      af[i] = *(const bf16x8*)(sA + (wr * 64 + i * 16 + l15) * 40 + lg * 8);
#pragma unroll
    for (int j = 0; j < 2; ++j)
      bfr[j] = *(const bf16x8*)(sB + (wc * 32 + j * 16 + l15) * 40 + lg * 8);
#pragma unroll
    for (int i = 0; i < 4; ++i)
#pragma unroll
      for (int j = 0; j < 2; ++j)
        acc[i][j] = __builtin_amdgcn_mfma_f32_16x16x32_bf16(af[i], bfr[j], acc[i][j], 0, 0, 0);
  }

  // ---- fused epilogue: bias, (scale, rope), pack, store ----
  const int cm = wbase + wc * 32;            // within-mat col base, 32-aligned
  const int hh = cm >> 5;                    // head
  const float bv0 = bias[cm + l15];
  const float bv1 = bias[cm + 16 + l15];
  const float SCL_Q = 0.17677669529663687f;  // hd^-0.5 (LOG2E applied in attn)

#pragma unroll
  for (int i = 0; i < 4; ++i) {
    const int m0 = rbase + wr * 64 + i * 16 + lg * 4;
    const int b = m0 >> 12, n0 = m0 & 4095;
    if (mat < 2) {
      short* dst = (mat == 0 ? Qo : Ko) + (size_t)(b * 8 + hh) * 131072 + (size_t)n0 * 32 + l15;
#pragma unroll
      for (int jj = 0; jj < 4; ++jj) {
        float v0 = acc[i][0][jj] + bv0;
        float v1 = acc[i][1][jj] + bv1;
        if (mat == 0) { v0 *= SCL_Q; v1 *= SCL_Q; }
        if (l15 < 8) {
          float ang = (float)(n0 + jj) * INV_TS[l15];
          float s = sinf(ang), c = cosf(ang);
          float r0 = v0 * c - v1 * s;
          float r1 = v1 * c + v0 * s;
          v0 = r0; v1 = r1;
        }
        dst[jj * 32]      = f2bf(v0);
        dst[jj * 32 + 16] = f2bf(v1);
      }
    } else {
      short* dstv = Vt + (size_t)(b * 8 + hh) * 131072 + n0;
#pragma unroll
      for (int j = 0; j < 2; ++j) {
        const float bv = j ? bv1 : bv0;
        short4v pk;
#pragma unroll
        for (int jj = 0; jj < 4; ++jj) pk[jj] = f2bf(acc[i][j][jj] + bv);
        *(short4v*)(dstv + (size_t)(j * 16 + l15) * 4096) = pk;
      }
    }
  }
}

// ---------------------------------------------------------------------------
// Flash attention v4 (round-4 known-good, VERBATIM): LDS-shared K/V
// (double-buffered, single barrier/iter), S^T orientation, per-wave P in LDS,
// K-split across blockIdx.z. Block 256 = 4 waves x 32 q-rows.
// Grid: (4096/128, 16, 2). Writes UNNORMALIZED partial O and partial den.
// ---------------------------------------------------------------------------
__global__ __launch_bounds__(256, 4) void attn_fwd(
    const short* __restrict__ Qg, const short* __restrict__ Kg, const short* __restrict__ Vg,
    const float* __restrict__ ab, const int* __restrict__ slp,
    float* __restrict__ Op, float* __restrict__ denp)
{
  __shared__ short sK[2][64 * 40];   // [key][dim], stride 40
  __shared__ short sV[2][32 * 72];   // [dim][key], stride 72
  __shared__ short sP[4][32 * 72];   // per-wave P [32 q][64 k], stride 72
  const int t = threadIdx.x, w = t >> 6, l = t & 63;
  const int l15 = l & 15, lg = l >> 4;
  const int bh = blockIdx.y, h = bh & 7;
  const int z = blockIdx.z;
  const int qb = blockIdx.x * 128 + w * 32;
  const int sl = *slp;

  const short* Qb = Qg + (size_t)bh * (4096 * 32);
  const short* Kb = Kg + (size_t)bh * (4096 * 32);
  const short* Vb = Vg + (size_t)bh * (32 * 4096);

  bf16x8 qf[2];
  qf[0] = *(const bf16x8*)(Qb + (size_t)(qb + l15) * 32 + lg * 8);
  qf[1] = *(const bf16x8*)(Qb + (size_t)(qb + 16 + l15) * 32 + lg * 8);

  const float LOG2E = 1.4426950408889634f;
  const float lbs = ab[h * 2] * LOG2E, lbd = ab[h * 2 + 1] * LOG2E;
  const int qv[2]  = { (qb + l15) / sl, (qb + 16 + l15) / sl };
  const int qlo[2] = { qv[0] * sl, qv[1] * sl };

  short* P = &sP[w][0];
  short* pw = P + l15 * 72 + lg * 4;
  const short* pr = P + l15 * 72 + lg * 8;

  const f32x4 fz = {0.f, 0.f, 0.f, 0.f};
  f32x4 Oacc[2][2];
  Oacc[0][0] = fz; Oacc[0][1] = fz; Oacc[1][0] = fz; Oacc[1][1] = fz;
  float den[2] = {0.f, 0.f};

  const int kt0 = z * 32, kt1 = kt0 + 32;
  const int kstart = kt0 * 64;

  const int kr = t >> 2, kc0 = (t & 3) * 8;
  const int vd = t >> 3, vk0 = (t & 7) * 8;
  const short* kg = Kb + (size_t)(kstart + kr) * 32 + kc0;
  const short* vg = Vb + (size_t)vd * 4096 + kstart + vk0;

  bf16x8 krg = *(const bf16x8*)kg;
  bf16x8 vrg = *(const bf16x8*)vg;
  *(bf16x8*)(&sK[0][0] + kr * 40 + kc0) = krg;
  *(bf16x8*)(&sV[0][0] + vd * 72 + vk0) = vrg;
  kg += 64 * 32; vg += 64;
  krg = *(const bf16x8*)kg;
  vrg = *(const bf16x8*)vg;
  __syncthreads();

  int kv = kstart / sl;
  int rem = (kv + 1) * sl - kstart;
  int cur = 0;

#pragma unroll 2
  for (int kt = kt0; kt < kt1; ++kt) {
    *(bf16x8*)(&sK[cur ^ 1][0] + kr * 40 + kc0) = krg;
    *(bf16x8*)(&sV[cur ^ 1][0] + vd * 72 + vk0) = vrg;
    const int adv = (kt + 2 < kt1) ? 1 : 0;
    kg += adv * (64 * 32); vg += adv * 64;
    krg = *(const bf16x8*)kg;
    vrg = *(const bf16x8*)vg;

    const short* sKc = &sK[cur][0];
    const short* sVc = &sV[cur][0];

    f32x4 S[2][4];
#pragma unroll
    for (int t4 = 0; t4 < 4; ++t4) {
      bf16x8 kf = *(const bf16x8*)(sKc + (t4 * 16 + l15) * 40 + lg * 8);
      S[0][t4] = __builtin_amdgcn_mfma_f32_16x16x32_bf16(kf, qf[0], fz, 0, 0, 0);
      S[1][t4] = __builtin_amdgcn_mfma_f32_16x16x32_bf16(kf, qf[1], fz, 0, 0, 0);
    }

    const int kb0 = kt * 64;
    if (rem >= 64) {
      float lb[2];
      lb[0] = (qv[0] == kv) ? lbs : lbd;
      lb[1] = (qv[1] == kv) ? lbs : lbd;
#pragma unroll
      for (int g = 0; g < 2; ++g)
#pragma unroll
        for (int t4 = 0; t4 < 4; ++t4) {
          float p0 = EXP2(S[g][t4][0] * LOG2E + lb[g]);
          float p1 = EXP2(S[g][t4][1] * LOG2E + lb[g]);
          float p2 = EXP2(S[g][t4][2] * LOG2E + lb[g]);
          float p3 = EXP2(S[g][t4][3] * LOG2E + lb[g]);
          den[g] += (p0 + p1) + (p2 + p3);
          u32x2 u; u.x = cvt_pk_bf16(p0, p1); u.y = cvt_pk_bf16(p2, p3);
          *(u32x2*)(pw + g * 1152 + t4 * 16) = u;
        }
    } else {
#pragma unroll
      for (int g = 0; g < 2; ++g)
#pragma unroll
        for (int t4 = 0; t4 < 4; ++t4) {
          const int gk = kb0 + t4 * 16 + lg * 4;
          float p[4];
#pragma unroll
          for (int j = 0; j < 4; ++j) {
            float lb = ((unsigned)(gk + j - qlo[g]) < (unsigned)sl) ? lbs : lbd;
            p[j] = EXP2(S[g][t4][j] * LOG2E + lb);
            den[g] += p[j];
          }
          u32x2 u; u.x = cvt_pk_bf16(p[0], p[1]); u.y = cvt_pk_bf16(p[2], p[3]);
          *(u32x2*)(pw + g * 1152 + t4 * 16) = u;
        }
    }
    rem -= 64;
    while (rem <= 0) { kv += 1; rem += sl; }

#pragma unroll
    for (int g = 0; g < 2; ++g)
#pragma unroll
      for (int kk = 0; kk < 2; ++kk) {
        bf16x8 pf = *(const bf16x8*)(pr + g * 1152 + kk * 32);
        bf16x8 vf0 = *(const bf16x8*)(sVc + l15 * 72 + kk * 32 + lg * 8);
        bf16x8 vf1 = *(const bf16x8*)(sVc + (16 + l15) * 72 + kk * 32 + lg * 8);
        Oacc[g][0] = __builtin_amdgcn_mfma_f32_16x16x32_bf16(pf, vf0, Oacc[g][0], 0, 0, 0);
        Oacc[g][1] = __builtin_amdgcn_mfma_f32_16x16x32_bf16(pf, vf1, Oacc[g][1], 0, 0, 0);
      }

    __syncthreads();
    cur ^= 1;
  }

#pragma unroll
  for (int g = 0; g < 2; ++g) {
    den[g] += __shfl_xor(den[g], 16, 64);
    den[g] += __shfl_xor(den[g], 32, 64);
  }

  const size_t zb = ((size_t)z * 16 + bh) * 4096;
  if (lg == 0) {
#pragma unroll
    for (int g = 0; g < 2; ++g)
      denp[zb + qb + g * 16 + l15] = den[g];
  }
#pragma unroll
  for (int g = 0; g < 2; ++g)
#pragma unroll
    for (int nt = 0; nt < 2; ++nt)
#pragma unroll
      for (int j = 0; j < 4; ++j) {
        const int n = qb + g * 16 + lg * 4 + j;
        Op[(zb + n) * 32 + nt * 16 + l15] = Oacc[g][nt][j];
      }
}

// ---------------------------------------------------------------------------
// Combine K-split partials: attno[b][n][h*32+d] = (O0+O1)/(d0+d1) as bf16.
// ---------------------------------------------------------------------------
__global__ __launch_bounds__(256) void combine(
    const float* __restrict__ Op, const float* __restrict__ denp,
    short* __restrict__ attno)
{
  const int id = blockIdx.x * 256 + threadIdx.x;   // 16*4096*8
  const int d4 = (id & 7) * 4;
  const int n  = (id >> 3) & 4095;
  const int bh = id >> 15;
  const size_t base = ((size_t)bh * 4096 + n) * 32 + d4;
  const size_t zoff = (size_t)16 * 4096 * 32;
  f32x4 o0 = *(const f32x4*)(Op + base);
  f32x4 o1 = *(const f32x4*)(Op + zoff + base);
  const float rd = 1.0f / (denp[bh * 4096 + n] + denp[16 * 4096 + bh * 4096 + n]);
  const int b = bh >> 3, hh = bh & 7;
  u32x2 u;
  u.x = cvt_pk_bf16((o0[0] + o1[0]) * rd, (o0[1] + o1[1]) * rd);
  u.y = cvt_pk_bf16((o0[2] + o1[2]) * rd, (o0[3] + o1[3]) * rd);
  *(u32x2*)(attno + ((size_t)(b * 4096 + n) * 256 + hh * 32 + d4)) = u;
}

// ---------------------------------------------------------------------------
// o-proj GEMM (round-4 template, A_BF16=1, OUT_BF16=0)
// ---------------------------------------------------------------------------
template<int A_BF16, int OUT_BF16>
__global__ __launch_bounds__(256) void gemm_mfma(
    const void* __restrict__ Ain,
    const float* __restrict__ W0, const float* __restrict__ W1, const float* __restrict__ W2,
    const float* __restrict__ b0, const float* __restrict__ b1, const float* __restrict__ b2,
    void* __restrict__ Cout, int Ntot)
{
  __shared__ short sA[128 * 40];
  __shared__ short sB[64 * 40];
  const int t = threadIdx.x;
  const int w = t >> 6, l = t & 63;
  const int l15 = l & 15, lg = l >> 4;
  const int rbase = blockIdx.x * 128;
  const int cgbase = blockIdx.y * 64;
  const int mat = cgbase >> 8;
  const float* W = (mat == 0) ? W0 : ((mat == 1) ? W1 : W2);
  const float* bias = (mat == 0) ? b0 : ((mat == 1) ? b1 : b2);
  const int wbase = cgbase & 255;

  const int ar = t >> 1, akc = (t & 1) * 16;
  const int br = t >> 2, bkc = (t & 3) * 8;

  const float* Bg = W + (size_t)(wbase + br) * 256 + bkc;
  const float* Agf = (const float*)Ain + (size_t)(rbase + ar) * 256 + akc;
  const short* Agh = (const short*)Ain + (size_t)(rbase + ar) * 256 + akc;

  const int wr = w >> 1, wc = w & 1;

  f32x4 acc[4][2];
#pragma unroll
  for (int i = 0; i < 4; ++i) {
    acc[i][0] = {0.f, 0.f, 0.f, 0.f};
    acc[i][1] = {0.f, 0.f, 0.f, 0.f};
  }

  for (int k0 = 0; k0 < 256; k0 += 32) {
    u32x4 pa0, pa1;
    if constexpr (A_BF16) {
      pa0 = *(const u32x4*)(Agh + k0);
      pa1 = *(const u32x4*)(Agh + k0 + 8);
    } else {
      f32x4 a0 = *(const f32x4*)(Agf + k0);
      f32x4 a1 = *(const f32x4*)(Agf + k0 + 4);
      f32x4 a2 = *(const f32x4*)(Agf + k0 + 8);
      f32x4 a3 = *(const f32x4*)(Agf + k0 + 12);
      pa0.x = cvt_pk_bf16(a0[0], a0[1]); pa0.y = cvt_pk_bf16(a0[2], a0[3]);
      pa0.z = cvt_pk_bf16(a1[0], a1[1]); pa0.w = cvt_pk_bf16(a1[2], a1[3]);
      pa1.x = cvt_pk_bf16(a2[0], a2[1]); pa1.y = cvt_pk_bf16(a2[2], a2[3]);
      pa1.z = cvt_pk_bf16(a3[0], a3[1]); pa1.w = cvt_pk_bf16(a3[2], a3[3]);
    }
    f32x4 bv0 = *(const f32x4*)(Bg + k0);
    f32x4 bv1 = *(const f32x4*)(Bg + k0 + 4);
    u32x4 pb;
    pb.x = cvt_pk_bf16(bv0[0], bv0[1]); pb.y = cvt_pk_bf16(bv0[2], bv0[3]);
    pb.z = cvt_pk_bf16(bv1[0], bv1[1]); pb.w = cvt_pk_bf16(bv1[2], bv1[3]);

    __syncthreads();
    *(u32x4*)(sA + ar * 40 + akc)     = pa0;
    *(u32x4*)(sA + ar * 40 + akc + 8) = pa1;
    *(u32x4*)(sB + br * 40 + bkc)     = pb;
    __syncthreads();

    bf16x8 af[4], bfr[2];
#pragma unroll
    for (int i = 0; i < 4; ++i)
      af[i] = *(const bf16x8*)(sA + (wr * 64 + i * 16 + l15) * 40 + lg * 8);
#pragma unroll
    for (int j = 0; j < 2; ++j)
      bfr[j] = *(const bf16x8*)(sB + (wc * 32 + j * 16 + l15) * 40 + lg * 8);
#pragma unroll
    for (int i = 0; i < 4; ++i)
#pragma unroll
      for (int j = 0; j < 2; ++j)
        acc[i][j] = __builtin_amdgcn_mfma_f32_16x16x32_bf16(af[i], bfr[j], acc[i][j], 0, 0, 0);
  }

#pragma unroll
  for (int i = 0; i < 4; ++i)
#pragma unroll
    for (int j = 0; j < 2; ++j) {
      const int n = cgbase + wc * 32 + j * 16 + l15;
      const float bv = bias[wbase + wc * 32 + j * 16 + l15];
#pragma unroll
      for (int jj = 0; jj < 4; ++jj) {
        const size_t m = (size_t)(rbase + wr * 64 + i * 16 + lg * 4 + jj);
        const float val = acc[i][j][jj] + bv;
        if constexpr (OUT_BF16) ((short*)Cout)[m * Ntot + n] = f2bf(val);
        else                    ((float*)Cout)[m * Ntot + n] = val;
      }
    }
}

// ---------------------------------------------------------------------------
extern "C" void kernel_launch(void* const* d_in, const int* in_sizes, int n_in,
                              void* d_out, int out_size, void* d_ws, size_t ws_size,
                              hipStream_t stream) {
  (void)in_sizes; (void)n_in; (void)out_size; (void)ws_size;
  const float* hs = (const float*)d_in[0];
  const float* qw = (const float*)d_in[1];
  const float* qb = (const float*)d_in[2];
  const float* kw = (const float*)d_in[3];
  const float* kb = (const float*)d_in[4];
  const float* vw = (const float*)d_in[5];
  const float* vb = (const float*)d_in[6];
  const float* ow = (const float*)d_in[7];
  const float* ob = (const float*)d_in[8];
  const float* ab = (const float*)d_in[9];
  const int* sl   = (const int*)d_in[11];
  float* out = (float*)d_out;

  char* ws = (char*)d_ws;
  float* Op   = (float*)(ws);                    // 2*16*4096*32*4 = 16,777,216
  short* Qbf  = (short*)(ws + 16777216);         // 4,194,304
  short* Kbf  = (short*)(ws + 20971520);         // 4,194,304
  short* Vtb  = (short*)(ws + 25165824);         // 4,194,304 (transposed)
  float* denp = (float*)(ws + 29360128);         // 524,288
  short* attno= (short*)(ws + 29884416);         // 4,194,304

  // QKV projection + fused rope/scale/pack/V-transpose  [bisect target]
  gemm_qkv_rope<<<dim3(64, 12), 256, 0, stream>>>(hs, qw, kw, vw, qb, kb, vb, Qbf, Kbf, Vtb);
  // attention (round-4 known-good), K-split in 2
  attn_fwd<<<dim3(32, 16, 2), 256, 0, stream>>>(Qbf, Kbf, Vtb, ab, sl, Op, denp);
  // merge partials -> bf16 attention output
  combine<<<dim3(2048), 256, 0, stream>>>(Op, denp, attno);
  // output projection
  gemm_mfma<1, 0><<<dim3(64, 4), 256, 0, stream>>>(attno, ow, ow, ow, ob, ob, ob, out, 256);
}